// Round 10
// baseline (341.074 us; speedup 1.0000x reference)
//
#include <hip/hip_runtime.h>

typedef __bf16 bf16x8 __attribute__((ext_vector_type(8)));
typedef float f32x4 __attribute__((ext_vector_type(4)));

// Async global->LDS, 16B per lane. LDS dest is wave-uniform base + lane*16.
__device__ inline void gload16(const __bf16* g, __bf16* l) {
  __builtin_amdgcn_global_load_lds(
      (const __attribute__((address_space(1))) unsigned int*)g,
      (__attribute__((address_space(3))) unsigned int*)l, 16, 0, 0);
}

// ---------------------------------------------------------------------------
// Fused prep — conv_bf16 + all transpose_w in ONE dispatch (round-9 win).
//   [0,4096)          conv: x fp32 -> xb bf16 (8 elems/thread)
//   [4096,5120)       Wq transpose (32x32 tiles)
//   [5120,5184)       Wk transpose (2x32)
//   [5184,5248)       Wv transpose (2x32)
//   [5248,6272)       Wo transpose (32x32, only if have_wot)
// ---------------------------------------------------------------------------
__device__ inline void tw_body(const float* __restrict__ W,
                               __bf16* __restrict__ WT, int Kd, int Nd,
                               int c0, int r0, int tid, __bf16* Ts)
{
#pragma unroll
  for (int i = 0; i < 4; i++) {
    int row = (tid >> 4) + i * 16, cv = (tid & 15) * 4;
    float4 w = *(const float4*)&W[(size_t)(r0 + row) * Nd + c0 + cv];
    Ts[(cv + 0) * 72 + row] = (__bf16)w.x;
    Ts[(cv + 1) * 72 + row] = (__bf16)w.y;
    Ts[(cv + 2) * 72 + row] = (__bf16)w.z;
    Ts[(cv + 3) * 72 + row] = (__bf16)w.w;
  }
  __syncthreads();
#pragma unroll
  for (int i = 0; i < 4; i++) {
    int n = (tid >> 4) + i * 16, kseg = (tid & 15) * 4;
    *(uint2*)&WT[(size_t)(c0 + n) * Kd + r0 + kseg] = *(uint2*)&Ts[n * 72 + kseg];
  }
}

__global__ __launch_bounds__(256) void prep_all(
    const float* __restrict__ x,  const float* __restrict__ Wq,
    const float* __restrict__ Wk, const float* __restrict__ Wv,
    const float* __restrict__ Wo,
    __bf16* __restrict__ xb,  __bf16* __restrict__ WqT,
    __bf16* __restrict__ WkT, __bf16* __restrict__ WvT,
    __bf16* __restrict__ WoT)
{
  __shared__ __bf16 Ts[64 * 72];
  const int b = blockIdx.x, tid = threadIdx.x;
  if (b < 4096) {
    size_t i = ((size_t)b * 256 + tid) * 8;
    float4 a = *(const float4*)&x[i];
    float4 c = *(const float4*)&x[i + 4];
    bf16x8 h;
    h[0] = (__bf16)a.x; h[1] = (__bf16)a.y; h[2] = (__bf16)a.z; h[3] = (__bf16)a.w;
    h[4] = (__bf16)c.x; h[5] = (__bf16)c.y; h[6] = (__bf16)c.z; h[7] = (__bf16)c.w;
    *(bf16x8*)&xb[i] = h;
  } else if (b < 5120) {
    int idx = b - 4096;
    tw_body(Wq, WqT, 2048, 2048, (idx & 31) * 64, (idx >> 5) * 64, tid, Ts);
  } else if (b < 5184) {
    int idx = b - 5120;
    tw_body(Wk, WkT, 2048, 128, (idx & 1) * 64, (idx >> 1) * 64, tid, Ts);
  } else if (b < 5248) {
    int idx = b - 5184;
    tw_body(Wv, WvT, 2048, 128, (idx & 1) * 64, (idx >> 1) * 64, tid, Ts);
  } else {
    int idx = b - 5248;
    tw_body(Wo, WoT, 2048, 2048, (idx & 31) * 64, (idx >> 5) * 64, tid, Ts);
  }
}

// ---------------------------------------------------------------------------
// Fused q/k/v projection GEMM (round-6 known-good: m97 structure + 2-phase
// dbuf prefetch + XCD-bijective remap). 128x128 tile, 256 thr. Unchanged.
// ---------------------------------------------------------------------------
__global__ __launch_bounds__(256) void gemm_qkv(
    const __bf16* __restrict__ A, const __bf16* __restrict__ WqT,
    const __bf16* __restrict__ WkT, const __bf16* __restrict__ WvT,
    __bf16* __restrict__ Cq, __bf16* __restrict__ Ck, __bf16* __restrict__ Cv)
{
  __shared__ __align__(16) __bf16 Asl[2][128 * 32];
  __shared__ __align__(16) __bf16 Bsl[2][128 * 32];
  const int tid = threadIdx.x, wave = tid >> 6, lane = tid & 63;
  const int quad = lane >> 4, l16 = lane & 15;
  int bid = blockIdx.x + 18 * blockIdx.y;       // linearized (x fastest)
  bid = (bid & 7) * 72 + (bid >> 3);            // XCD-contiguous remap
  const int nb = bid % 18, m0 = (bid / 18) * 128;
  const __bf16* BT; __bf16* C; int ldC, c0;
  if (nb < 16)       { BT = WqT + (size_t)nb * 128 * 2048; C = Cq; ldC = 2048; c0 = nb * 128; }
  else if (nb == 16) { BT = WkT; C = Ck; ldC = 128; c0 = 0; }
  else               { BT = WvT; C = Cv; ldC = 128; c0 = 0; }
  const int wm = (wave >> 1) * 64, wn = (wave & 1) * 64;
  const int lrow = lane >> 2, lseg = (lane & 3) * 8;

  f32x4 acc[4][4];
#pragma unroll
  for (int i = 0; i < 4; i++)
#pragma unroll
    for (int j = 0; j < 4; j++) acc[i][j] = (f32x4){0.f, 0.f, 0.f, 0.f};

#pragma unroll
  for (int c = 0; c < 2; c++) {
    int ch = wave * 2 + c;
    gload16(&A[(size_t)(m0 + ch * 16 + lrow) * 2048 + lseg], &Asl[0][ch * 512]);
    gload16(&BT[(size_t)(ch * 16 + lrow) * 2048 + lseg], &Bsl[0][ch * 512]);
  }
  __syncthreads();

  int cur = 0;
  for (int k0 = 0; k0 < 2048; k0 += 32) {
    if (k0 + 32 < 2048) {
#pragma unroll
      for (int c = 0; c < 2; c++) {
        int ch = wave * 2 + c;
        gload16(&A[(size_t)(m0 + ch * 16 + lrow) * 2048 + k0 + 32 + lseg],
                &Asl[cur ^ 1][ch * 512]);
        gload16(&BT[(size_t)(ch * 16 + lrow) * 2048 + k0 + 32 + lseg],
                &Bsl[cur ^ 1][ch * 512]);
      }
    }

    bf16x8 af[4], bf[4];
#pragma unroll
    for (int i = 0; i < 4; i++)
      af[i] = *(const bf16x8*)&Asl[cur][(wm + i * 16 + l16) * 32 + quad * 8];
#pragma unroll
    for (int i = 0; i < 4; i++)
      bf[i] = *(const bf16x8*)&Bsl[cur][(wn + i * 16 + l16) * 32 + quad * 8];
#pragma unroll
    for (int mi = 0; mi < 4; mi++)
#pragma unroll
      for (int ni = 0; ni < 4; ni++)
        acc[mi][ni] = __builtin_amdgcn_mfma_f32_16x16x32_bf16(
            af[mi], bf[ni], acc[mi][ni], 0, 0, 0);

    __syncthreads();
    cur ^= 1;
  }

#pragma unroll
  for (int mi = 0; mi < 4; mi++)
#pragma unroll
    for (int ni = 0; ni < 4; ni++)
#pragma unroll
      for (int r = 0; r < 4; r++) {
        int row = m0 + wm + mi * 16 + quad * 4 + r;
        int col = c0 + wn + ni * 16 + l16;
        C[(size_t)row * ldC + col] = (__bf16)acc[mi][ni][r];
      }
}

// ---------------------------------------------------------------------------
// Final GEMM, pure-bf16 path (round-6 known-good). Unchanged.
// ---------------------------------------------------------------------------
__global__ __launch_bounds__(256) void gemm_out_bt(
    const __bf16* __restrict__ A, const __bf16* __restrict__ BT,
    float* __restrict__ Cp)
{
  __shared__ __align__(16) __bf16 Asl[2][128 * 32];
  __shared__ __align__(16) __bf16 Bsl[2][128 * 32];
  const int tid = threadIdx.x, wave = tid >> 6, lane = tid & 63;
  const int quad = lane >> 4, l16 = lane & 15;
  int bid = blockIdx.x + 16 * blockIdx.y;       // linearized (x fastest)
  bid = (bid & 7) * 64 + (bid >> 3);            // XCD-contiguous remap
  const int n0 = (bid & 15) * 128, m0 = (bid >> 4) * 128;
  const int wm = (wave >> 1) * 64, wn = (wave & 1) * 64;
  const int lrow = lane >> 2, lseg = (lane & 3) * 8;

  f32x4 acc[4][4];
#pragma unroll
  for (int i = 0; i < 4; i++)
#pragma unroll
    for (int j = 0; j < 4; j++) acc[i][j] = (f32x4){0.f, 0.f, 0.f, 0.f};

#pragma unroll
  for (int c = 0; c < 2; c++) {
    int ch = wave * 2 + c;
    gload16(&A[(size_t)(m0 + ch * 16 + lrow) * 2048 + lseg], &Asl[0][ch * 512]);
    gload16(&BT[(size_t)(n0 + ch * 16 + lrow) * 2048 + lseg], &Bsl[0][ch * 512]);
  }
  __syncthreads();

  int cur = 0;
  for (int k0 = 0; k0 < 2048; k0 += 32) {
    if (k0 + 32 < 2048) {
#pragma unroll
      for (int c = 0; c < 2; c++) {
        int ch = wave * 2 + c;
        gload16(&A[(size_t)(m0 + ch * 16 + lrow) * 2048 + k0 + 32 + lseg],
                &Asl[cur ^ 1][ch * 512]);
        gload16(&BT[(size_t)(n0 + ch * 16 + lrow) * 2048 + k0 + 32 + lseg],
                &Bsl[cur ^ 1][ch * 512]);
      }
    }

    bf16x8 af[4], bf[4];
#pragma unroll
    for (int i = 0; i < 4; i++)
      af[i] = *(const bf16x8*)&Asl[cur][(wm + i * 16 + l16) * 32 + quad * 8];
#pragma unroll
    for (int i = 0; i < 4; i++)
      bf[i] = *(const bf16x8*)&Bsl[cur][(wn + i * 16 + l16) * 32 + quad * 8];
#pragma unroll
    for (int mi = 0; mi < 4; mi++)
#pragma unroll
      for (int ni = 0; ni < 4; ni++)
        acc[mi][ni] = __builtin_amdgcn_mfma_f32_16x16x32_bf16(
            af[mi], bf[ni], acc[mi][ni], 0, 0, 0);

    __syncthreads();
    cur ^= 1;
  }

#pragma unroll
  for (int mi = 0; mi < 4; mi++)
#pragma unroll
    for (int ni = 0; ni < 4; ni++)
#pragma unroll
      for (int r = 0; r < 4; r++) {
        int row = m0 + wm + mi * 16 + quad * 4 + r;
        int col = n0 + wn + ni * 16 + l16;
        Cp[(size_t)row * 2048 + col] = acc[mi][ni][r];
      }
}

// ---------------------------------------------------------------------------
// Final GEMM, fallback (ws too small for WoT). Unchanged.
// ---------------------------------------------------------------------------
__global__ __launch_bounds__(256) void gemm_out_f32b(
    const __bf16* __restrict__ A, const float* __restrict__ B,
    float* __restrict__ Cp)
{
  __shared__ __align__(16) __bf16 Asl[128 * 32];
  __shared__ __align__(16) __bf16 BsT[128 * 32];
  const int tid = threadIdx.x, wave = tid >> 6, lane = tid & 63;
  const int quad = lane >> 4, l16 = lane & 15;
  const int n0 = blockIdx.x * 128, m0 = blockIdx.y * 128;
  const int wm = (wave >> 1) * 64, wn = (wave & 1) * 64;
  const int lrow = lane >> 2, lseg = (lane & 3) * 8;
  const int kg = (tid >> 5) * 4, ng = (tid & 31) * 4;

  f32x4 acc[4][4];
#pragma unroll
  for (int i = 0; i < 4; i++)
#pragma unroll
    for (int j = 0; j < 4; j++) acc[i][j] = (f32x4){0.f, 0.f, 0.f, 0.f};

  for (int k0 = 0; k0 < 2048; k0 += 32) {
    __syncthreads();
#pragma unroll
    for (int c = 0; c < 2; c++) {
      int ch = wave * 2 + c;
      gload16(&A[(size_t)(m0 + ch * 16 + lrow) * 2048 + k0 + lseg], &Asl[ch * 512]);
    }
    __bf16 h[4][4];
#pragma unroll
    for (int i = 0; i < 4; i++) {
      float4 w = *(const float4*)&B[(size_t)(k0 + kg + i) * 2048 + n0 + ng];
      h[i][0] = (__bf16)w.x; h[i][1] = (__bf16)w.y;
      h[i][2] = (__bf16)w.z; h[i][3] = (__bf16)w.w;
    }
#pragma unroll
    for (int j = 0; j < 4; j++) {
      int n = ng + j;
      int pb = ((kg >> 3) + (n >> 2)) & 3;
      __bf16 o4[4] = {h[0][j], h[1][j], h[2][j], h[3][j]};
      *(uint2*)&BsT[n * 32 + pb * 8 + (kg & 7)] = *(uint2*)o4;
    }
    __syncthreads();

    bf16x8 af[4], bf[4];
#pragma unroll
    for (int i = 0; i < 4; i++)
      af[i] = *(const bf16x8*)&Asl[(wm + i * 16 + l16) * 32 + quad * 8];
#pragma unroll
    for (int i = 0; i < 4; i++) {
      int n = wn + i * 16 + l16;
      int pb = (quad + (n >> 2)) & 3;
      bf[i] = *(const bf16x8*)&BsT[n * 32 + pb * 8];
    }
#pragma unroll
    for (int mi = 0; mi < 4; mi++)
#pragma unroll
      for (int ni = 0; ni < 4; ni++)
        acc[mi][ni] = __builtin_amdgcn_mfma_f32_16x16x32_bf16(
            af[mi], bf[ni], acc[mi][ni], 0, 0, 0);
  }

#pragma unroll
  for (int mi = 0; mi < 4; mi++)
#pragma unroll
    for (int ni = 0; ni < 4; ni++)
#pragma unroll
      for (int r = 0; r < 4; r++) {
        int row = m0 + wm + mi * 16 + quad * 4 + r;
        int col = n0 + wn + ni * 16 + l16;
        Cp[(size_t)row * 2048 + col] = acc[mi][ni][r];
      }
}

// ---------------------------------------------------------------------------
// MQA causal flash attention, MFMA, fixed-base streaming softmax.
// ROUND 18: (a) K LDS-staging REMOVED — K panel (512 KB/batch) is L2-
// resident and shared by all blocks; K-frag is a lane-contiguous 16B global
// load, consumed by MFMA directly (m169: stage only when data doesn't
// cache-fit). Deletes 1024 LDS stores + padded ds_reads per chunk; LDS
// 54.3 -> 36.9 KB. Row idx sc+kt*16+l16 <= 2047 always (no clamp needed).
// (b) T5 s_setprio(1) around both MFMA clusters (m191 attn regime: multi-
// block CU, independent phases). Rest byte-identical to round-9 best.
// ---------------------------------------------------------------------------
#define VT_LD 72
#define PR_LD 72

__global__ __launch_bounds__(256) void mqa_attn_mfma(
    const __bf16* Q, const __bf16* __restrict__ Km,
    const __bf16* __restrict__ Vm, __bf16* O)
{
  __shared__ __align__(16) __bf16 VsT[128 * VT_LD];
  __shared__ __align__(16) __bf16 Pr[4][32 * PR_LD];

  const int tid = threadIdx.x, wave = tid >> 6, lane = tid & 63;
  const int quad = lane >> 4, l16 = lane & 15;
  const int t = blockIdx.x >> 1, bat = blockIdx.x & 1;
  const int hg = blockIdx.y & 3, flip = blockIdx.y >> 2;
  const int qt = flip ? (63 - t) : t;
  const int h = hg * 4 + wave;
  const int q0 = qt * 32;
  const size_t qgrow = (size_t)bat * 2048 + q0;
  const float SCL2 = 0.08838834764831845f * 1.4426950408889634f;  // scale*log2e

  // Q regs: lane holds Q[qrow=l16(+16mi)][d=ks*32+quad*8+j] — serves as the
  // B-frag of Q (B[k=d][n=qrow]) for the S^T MFMA.
  bf16x8 qf[2][4];
#pragma unroll
  for (int mi = 0; mi < 2; mi++)
#pragma unroll
    for (int ks = 0; ks < 4; ks++)
      qf[mi][ks] = *(const bf16x8*)(Q + (qgrow + mi * 16 + l16) * 2048 +
                                    h * 128 + ks * 32 + quad * 8);

  bf16x8 ones;
#pragma unroll
  for (int i = 0; i < 8; i++) ones[i] = (__bf16)1.0f;

  f32x4 oa[2][8];
#pragma unroll
  for (int mi = 0; mi < 2; mi++)
#pragma unroll
    for (int nt = 0; nt < 8; nt++) oa[mi][nt] = (f32x4){0.f, 0.f, 0.f, 0.f};
  f32x4 lacc[2];
  lacc[0] = (f32x4){0.f, 0.f, 0.f, 0.f};
  lacc[1] = (f32x4){0.f, 0.f, 0.f, 0.f};

  const __bf16* Kb = Km + (size_t)bat * 2048 * 128;
  const __bf16* Vb = Vm + (size_t)bat * 2048 * 128;
  const int qmax = q0 + 31;

  for (int sc = 0; sc <= qmax; sc += 64) {
    __syncthreads();   // all waves done reading VsT before restage
    // --- stage V transposed [d][key], rotated 8-key blocks (unchanged) ---
#pragma unroll
    for (int i = 0; i < 2; i++) {
      int g = tid + i * 256;
      int dg = (g & 31) * 4, kg2 = (g >> 5) * 4;
      union { uint2 u; unsigned short s[4]; } a[4], o;
#pragma unroll
      for (int i2 = 0; i2 < 4; i2++) {
        int kr = sc + kg2 + i2; if (kr > 2047) kr = 2047;
        a[i2].u = *(const uint2*)&Vb[(size_t)kr * 128 + dg];
      }
#pragma unroll
      for (int j = 0; j < 4; j++) {
        int d = dg + j;
        int pb = ((kg2 >> 3) + (d >> 2)) & 7;
        o.s[0] = a[0].s[j]; o.s[1] = a[1].s[j];
        o.s[2] = a[2].s[j]; o.s[3] = a[3].s[j];
        *(uint2*)&VsT[d * VT_LD + pb * 8 + (kg2 & 7)] = o.u;
      }
    }
    __syncthreads();

    // --- S^T = K @ Q^T, K-frags DIRECT from global (L2-resident panel) ---
    const __bf16* Kc = Kb + (size_t)sc * 128;
    f32x4 sf[2][4];
#pragma unroll
    for (int mi = 0; mi < 2; mi++)
#pragma unroll
      for (int kt = 0; kt < 4; kt++) sf[mi][kt] = (f32x4){0.f, 0.f, 0.f, 0.f};
    __builtin_amdgcn_s_setprio(1);
#pragma unroll
    for (int ks = 0; ks < 4; ks++)
#pragma unroll
      for (int kt = 0; kt < 4; kt++) {
        bf16x8 kf = *(const bf16x8*)&Kc[(size_t)(kt * 16 + l16) * 128 +
                                        ks * 32 + quad * 8];
        sf[0][kt] = __builtin_amdgcn_mfma_f32_16x16x32_bf16(kf, qf[0][ks], sf[0][kt], 0, 0, 0);
        sf[1][kt] = __builtin_amdgcn_mfma_f32_16x16x32_bf16(kf, qf[1][ks], sf[1][kt], 0, 0, 0);
      }
    __builtin_amdgcn_s_setprio(0);

    // --- P = exp2(S*SCL2), Pr[qrow][key] via b64 (4 contiguous keys/reg) ---
    __bf16* prw = Pr[wave];
    if (sc + 64 > q0) {  // uniform: only the diagonal chunk needs the mask
#pragma unroll
      for (int mi = 0; mi < 2; mi++) {
        int qrow = q0 + mi * 16 + l16;
#pragma unroll
        for (int kt = 0; kt < 4; kt++) {
          int kbase = sc + kt * 16 + quad * 4;
          __bf16 h4[4];
#pragma unroll
          for (int r = 0; r < 4; r++) {
            float p = (kbase + r <= qrow) ? exp2f(sf[mi][kt][r] * SCL2) : 0.f;
            h4[r] = (__bf16)p;
          }
          *(uint2*)&prw[(mi * 16 + l16) * PR_LD + kt * 16 + quad * 4] = *(uint2*)h4;
        }
      }
    } else {
#pragma unroll
      for (int mi = 0; mi < 2; mi++)
#pragma unroll
        for (int kt = 0; kt < 4; kt++) {
          __bf16 h4[4];
#pragma unroll
          for (int r = 0; r < 4; r++) h4[r] = (__bf16)exp2f(sf[mi][kt][r] * SCL2);
          *(uint2*)&prw[(mi * 16 + l16) * PR_LD + kt * 16 + quad * 4] = *(uint2*)h4;
        }
    }

    // --- O += P @ V ; l += P @ 1 (rowsum via MFMA) ---
    __builtin_amdgcn_s_setprio(1);
#pragma unroll
    for (int ks2 = 0; ks2 < 2; ks2++) {
      bf16x8 pf0 = *(const bf16x8*)&prw[(l16) * PR_LD + ks2 * 32 + quad * 8];
      bf16x8 pf1 = *(const bf16x8*)&prw[(16 + l16) * PR_LD + ks2 * 32 + quad * 8];
      lacc[0] = __builtin_amdgcn_mfma_f32_16x16x32_bf16(pf0, ones, lacc[0], 0, 0, 0);
      lacc[1] = __builtin_amdgcn_mfma_f32_16x16x32_bf16(pf1, ones, lacc[1], 0, 0, 0);
#pragma unroll
      for (int nt = 0; nt < 8; nt++) {
        int d = nt * 16 + l16;
        int pb = ((ks2 * 4 + quad) + (d >> 2)) & 7;
        bf16x8 vf = *(const bf16x8*)&VsT[d * VT_LD + pb * 8];
        oa[0][nt] = __builtin_amdgcn_mfma_f32_16x16x32_bf16(pf0, vf, oa[0][nt], 0, 0, 0);
        oa[1][nt] = __builtin_amdgcn_mfma_f32_16x16x32_bf16(pf1, vf, oa[1][nt], 0, 0, 0);
      }
    }
    __builtin_amdgcn_s_setprio(0);
  }

  // epilogue: O[row] = oa / l   (l > 0: diagonal key always unmasked)
#pragma unroll
  for (int mi = 0; mi < 2; mi++)
#pragma unroll
    for (int r = 0; r < 4; r++) {
      float inv = 1.f / lacc[mi][r];
      size_t row = qgrow + mi * 16 + quad * 4 + r;
#pragma unroll
      for (int nt = 0; nt < 8; nt++)
        O[row * 2048 + h * 128 + nt * 16 + l16] = (__bf16)(oa[mi][nt][r] * inv);
    }
}

// ---------------------------------------------------------------------------
// Memory plan:
//   ws   : q / at (in-place) 16.78 MB | WoT 8.39 MB (only if ws_size allows)
//   d_out: xb | WqT | WkT | WvT | k | v 28.3 MB  (dead before final GEMM)
// Dispatches: prep_all -> gemm_qkv -> mqa_attn -> gemm_out  (4 total)
// ---------------------------------------------------------------------------
extern "C" void kernel_launch(void* const* d_in, const int* in_sizes, int n_in,
                              void* d_out, int out_size, void* d_ws, size_t ws_size,
                              hipStream_t stream) {
  const float* x  = (const float*)d_in[0];
  const float* Wq = (const float*)d_in[1];
  const float* Wk = (const float*)d_in[2];
  const float* Wv = (const float*)d_in[3];
  const float* Wo = (const float*)d_in[4];
  float* out = (float*)d_out;

  __bf16* q   = (__bf16*)d_ws;
  __bf16* WoT = (__bf16*)((char*)d_ws + 16777216);
  const bool have_wot = ws_size >= (size_t)(16777216 + 8388608);

  char* ob = (char*)d_out;
  __bf16* xb  = (__bf16*)(ob);
  __bf16* WqT = (__bf16*)(ob + 16777216);
  __bf16* WkT = (__bf16*)(ob + 25165824);
  __bf16* WvT = (__bf16*)(ob + 25690112);
  __bf16* kb  = (__bf16*)(ob + 26214400);
  __bf16* vb  = (__bf16*)(ob + 27262976);

  dim3 blk(256);
  const int prep_blocks = have_wot ? 6272 : 5248;
  prep_all<<<prep_blocks, blk, 0, stream>>>(x, Wq, Wk, Wv, Wo,
                                            xb, WqT, WkT, WvT, WoT);
  gemm_qkv<<<dim3(18, 32), blk, 0, stream>>>(xb, WqT, WkT, WvT, q, kb, vb);
  mqa_attn_mfma<<<dim3(64, 8, 1), blk, 0, stream>>>(q, kb, vb, q);
  if (have_wot)
    gemm_out_bt<<<dim3(16, 32), blk, 0, stream>>>(q, WoT, out);
  else
    gemm_out_f32b<<<dim3(16, 32), blk, 0, stream>>>(q, Wo, out);
}

// Round 13
// 286.376 us; speedup vs baseline: 1.1910x; 1.1910x over previous
//
#include <hip/hip_runtime.h>

typedef __bf16 bf16x8 __attribute__((ext_vector_type(8)));
typedef float f32x4 __attribute__((ext_vector_type(4)));

// Async global->LDS, 16B per lane. LDS dest is wave-uniform base + lane*16.
__device__ inline void gload16(const __bf16* g, __bf16* l) {
  __builtin_amdgcn_global_load_lds(
      (const __attribute__((address_space(1))) unsigned int*)g,
      (__attribute__((address_space(3))) unsigned int*)l, 16, 0, 0);
}

// ---------------------------------------------------------------------------
// Fused prep — conv_bf16 + all transpose_w in ONE dispatch (round-9 win).
//   [0,4096)          conv: x fp32 -> xb bf16 (8 elems/thread)
//   [4096,5120)       Wq transpose (32x32 tiles)
//   [5120,5184)       Wk transpose (2x32)
//   [5184,5248)       Wv transpose (2x32)
//   [5248,6272)       Wo transpose (32x32, only if have_wot)
// ---------------------------------------------------------------------------
__device__ inline void tw_body(const float* __restrict__ W,
                               __bf16* __restrict__ WT, int Kd, int Nd,
                               int c0, int r0, int tid, __bf16* Ts)
{
#pragma unroll
  for (int i = 0; i < 4; i++) {
    int row = (tid >> 4) + i * 16, cv = (tid & 15) * 4;
    float4 w = *(const float4*)&W[(size_t)(r0 + row) * Nd + c0 + cv];
    Ts[(cv + 0) * 72 + row] = (__bf16)w.x;
    Ts[(cv + 1) * 72 + row] = (__bf16)w.y;
    Ts[(cv + 2) * 72 + row] = (__bf16)w.z;
    Ts[(cv + 3) * 72 + row] = (__bf16)w.w;
  }
  __syncthreads();
#pragma unroll
  for (int i = 0; i < 4; i++) {
    int n = (tid >> 4) + i * 16, kseg = (tid & 15) * 4;
    *(uint2*)&WT[(size_t)(c0 + n) * Kd + r0 + kseg] = *(uint2*)&Ts[n * 72 + kseg];
  }
}

__global__ __launch_bounds__(256) void prep_all(
    const float* __restrict__ x,  const float* __restrict__ Wq,
    const float* __restrict__ Wk, const float* __restrict__ Wv,
    const float* __restrict__ Wo,
    __bf16* __restrict__ xb,  __bf16* __restrict__ WqT,
    __bf16* __restrict__ WkT, __bf16* __restrict__ WvT,
    __bf16* __restrict__ WoT)
{
  __shared__ __bf16 Ts[64 * 72];
  const int b = blockIdx.x, tid = threadIdx.x;
  if (b < 4096) {
    size_t i = ((size_t)b * 256 + tid) * 8;
    float4 a = *(const float4*)&x[i];
    float4 c = *(const float4*)&x[i + 4];
    bf16x8 h;
    h[0] = (__bf16)a.x; h[1] = (__bf16)a.y; h[2] = (__bf16)a.z; h[3] = (__bf16)a.w;
    h[4] = (__bf16)c.x; h[5] = (__bf16)c.y; h[6] = (__bf16)c.z; h[7] = (__bf16)c.w;
    *(bf16x8*)&xb[i] = h;
  } else if (b < 5120) {
    int idx = b - 4096;
    tw_body(Wq, WqT, 2048, 2048, (idx & 31) * 64, (idx >> 5) * 64, tid, Ts);
  } else if (b < 5184) {
    int idx = b - 5120;
    tw_body(Wk, WkT, 2048, 128, (idx & 1) * 64, (idx >> 1) * 64, tid, Ts);
  } else if (b < 5248) {
    int idx = b - 5184;
    tw_body(Wv, WvT, 2048, 128, (idx & 1) * 64, (idx >> 1) * 64, tid, Ts);
  } else {
    int idx = b - 5248;
    tw_body(Wo, WoT, 2048, 2048, (idx & 31) * 64, (idx >> 5) * 64, tid, Ts);
  }
}

// ---------------------------------------------------------------------------
// Fused q/k/v projection GEMM (round-6 known-good: m97 structure + 2-phase
// dbuf prefetch + XCD-bijective remap). 128x128 tile, 256 thr. Unchanged.
// ---------------------------------------------------------------------------
__global__ __launch_bounds__(256) void gemm_qkv(
    const __bf16* __restrict__ A, const __bf16* __restrict__ WqT,
    const __bf16* __restrict__ WkT, const __bf16* __restrict__ WvT,
    __bf16* __restrict__ Cq, __bf16* __restrict__ Ck, __bf16* __restrict__ Cv)
{
  __shared__ __align__(16) __bf16 Asl[2][128 * 32];
  __shared__ __align__(16) __bf16 Bsl[2][128 * 32];
  const int tid = threadIdx.x, wave = tid >> 6, lane = tid & 63;
  const int quad = lane >> 4, l16 = lane & 15;
  int bid = blockIdx.x + 18 * blockIdx.y;       // linearized (x fastest)
  bid = (bid & 7) * 72 + (bid >> 3);            // XCD-contiguous remap
  const int nb = bid % 18, m0 = (bid / 18) * 128;
  const __bf16* BT; __bf16* C; int ldC, c0;
  if (nb < 16)       { BT = WqT + (size_t)nb * 128 * 2048; C = Cq; ldC = 2048; c0 = nb * 128; }
  else if (nb == 16) { BT = WkT; C = Ck; ldC = 128; c0 = 0; }
  else               { BT = WvT; C = Cv; ldC = 128; c0 = 0; }
  const int wm = (wave >> 1) * 64, wn = (wave & 1) * 64;
  const int lrow = lane >> 2, lseg = (lane & 3) * 8;

  f32x4 acc[4][4];
#pragma unroll
  for (int i = 0; i < 4; i++)
#pragma unroll
    for (int j = 0; j < 4; j++) acc[i][j] = (f32x4){0.f, 0.f, 0.f, 0.f};

#pragma unroll
  for (int c = 0; c < 2; c++) {
    int ch = wave * 2 + c;
    gload16(&A[(size_t)(m0 + ch * 16 + lrow) * 2048 + lseg], &Asl[0][ch * 512]);
    gload16(&BT[(size_t)(ch * 16 + lrow) * 2048 + lseg], &Bsl[0][ch * 512]);
  }
  __syncthreads();

  int cur = 0;
  for (int k0 = 0; k0 < 2048; k0 += 32) {
    if (k0 + 32 < 2048) {
#pragma unroll
      for (int c = 0; c < 2; c++) {
        int ch = wave * 2 + c;
        gload16(&A[(size_t)(m0 + ch * 16 + lrow) * 2048 + k0 + 32 + lseg],
                &Asl[cur ^ 1][ch * 512]);
        gload16(&BT[(size_t)(ch * 16 + lrow) * 2048 + k0 + 32 + lseg],
                &Bsl[cur ^ 1][ch * 512]);
      }
    }

    bf16x8 af[4], bf[4];
#pragma unroll
    for (int i = 0; i < 4; i++)
      af[i] = *(const bf16x8*)&Asl[cur][(wm + i * 16 + l16) * 32 + quad * 8];
#pragma unroll
    for (int i = 0; i < 4; i++)
      bf[i] = *(const bf16x8*)&Bsl[cur][(wn + i * 16 + l16) * 32 + quad * 8];
#pragma unroll
    for (int mi = 0; mi < 4; mi++)
#pragma unroll
      for (int ni = 0; ni < 4; ni++)
        acc[mi][ni] = __builtin_amdgcn_mfma_f32_16x16x32_bf16(
            af[mi], bf[ni], acc[mi][ni], 0, 0, 0);

    __syncthreads();
    cur ^= 1;
  }

#pragma unroll
  for (int mi = 0; mi < 4; mi++)
#pragma unroll
    for (int ni = 0; ni < 4; ni++)
#pragma unroll
      for (int r = 0; r < 4; r++) {
        int row = m0 + wm + mi * 16 + quad * 4 + r;
        int col = c0 + wn + ni * 16 + l16;
        C[(size_t)row * ldC + col] = (__bf16)acc[mi][ni][r];
      }
}

// ---------------------------------------------------------------------------
// Final GEMM, pure-bf16 path (round-6 known-good). Unchanged.
// ---------------------------------------------------------------------------
__global__ __launch_bounds__(256) void gemm_out_bt(
    const __bf16* __restrict__ A, const __bf16* __restrict__ BT,
    float* __restrict__ Cp)
{
  __shared__ __align__(16) __bf16 Asl[2][128 * 32];
  __shared__ __align__(16) __bf16 Bsl[2][128 * 32];
  const int tid = threadIdx.x, wave = tid >> 6, lane = tid & 63;
  const int quad = lane >> 4, l16 = lane & 15;
  int bid = blockIdx.x + 16 * blockIdx.y;       // linearized (x fastest)
  bid = (bid & 7) * 64 + (bid >> 3);            // XCD-contiguous remap
  const int n0 = (bid & 15) * 128, m0 = (bid >> 4) * 128;
  const int wm = (wave >> 1) * 64, wn = (wave & 1) * 64;
  const int lrow = lane >> 2, lseg = (lane & 3) * 8;

  f32x4 acc[4][4];
#pragma unroll
  for (int i = 0; i < 4; i++)
#pragma unroll
    for (int j = 0; j < 4; j++) acc[i][j] = (f32x4){0.f, 0.f, 0.f, 0.f};

#pragma unroll
  for (int c = 0; c < 2; c++) {
    int ch = wave * 2 + c;
    gload16(&A[(size_t)(m0 + ch * 16 + lrow) * 2048 + lseg], &Asl[0][ch * 512]);
    gload16(&BT[(size_t)(n0 + ch * 16 + lrow) * 2048 + lseg], &Bsl[0][ch * 512]);
  }
  __syncthreads();

  int cur = 0;
  for (int k0 = 0; k0 < 2048; k0 += 32) {
    if (k0 + 32 < 2048) {
#pragma unroll
      for (int c = 0; c < 2; c++) {
        int ch = wave * 2 + c;
        gload16(&A[(size_t)(m0 + ch * 16 + lrow) * 2048 + k0 + 32 + lseg],
                &Asl[cur ^ 1][ch * 512]);
        gload16(&BT[(size_t)(n0 + ch * 16 + lrow) * 2048 + k0 + 32 + lseg],
                &Bsl[cur ^ 1][ch * 512]);
      }
    }

    bf16x8 af[4], bf[4];
#pragma unroll
    for (int i = 0; i < 4; i++)
      af[i] = *(const bf16x8*)&Asl[cur][(wm + i * 16 + l16) * 32 + quad * 8];
#pragma unroll
    for (int i = 0; i < 4; i++)
      bf[i] = *(const bf16x8*)&Bsl[cur][(wn + i * 16 + l16) * 32 + quad * 8];
#pragma unroll
    for (int mi = 0; mi < 4; mi++)
#pragma unroll
      for (int ni = 0; ni < 4; ni++)
        acc[mi][ni] = __builtin_amdgcn_mfma_f32_16x16x32_bf16(
            af[mi], bf[ni], acc[mi][ni], 0, 0, 0);

    __syncthreads();
    cur ^= 1;
  }

#pragma unroll
  for (int mi = 0; mi < 4; mi++)
#pragma unroll
    for (int ni = 0; ni < 4; ni++)
#pragma unroll
      for (int r = 0; r < 4; r++) {
        int row = m0 + wm + mi * 16 + quad * 4 + r;
        int col = n0 + wn + ni * 16 + l16;
        Cp[(size_t)row * 2048 + col] = acc[mi][ni][r];
      }
}

// ---------------------------------------------------------------------------
// Final GEMM, fallback (ws too small for WoT). Unchanged.
// ---------------------------------------------------------------------------
__global__ __launch_bounds__(256) void gemm_out_f32b(
    const __bf16* __restrict__ A, const float* __restrict__ B,
    float* __restrict__ Cp)
{
  __shared__ __align__(16) __bf16 Asl[128 * 32];
  __shared__ __align__(16) __bf16 BsT[128 * 32];
  const int tid = threadIdx.x, wave = tid >> 6, lane = tid & 63;
  const int quad = lane >> 4, l16 = lane & 15;
  const int n0 = blockIdx.x * 128, m0 = blockIdx.y * 128;
  const int wm = (wave >> 1) * 64, wn = (wave & 1) * 64;
  const int lrow = lane >> 2, lseg = (lane & 3) * 8;
  const int kg = (tid >> 5) * 4, ng = (tid & 31) * 4;

  f32x4 acc[4][4];
#pragma unroll
  for (int i = 0; i < 4; i++)
#pragma unroll
    for (int j = 0; j < 4; j++) acc[i][j] = (f32x4){0.f, 0.f, 0.f, 0.f};

  for (int k0 = 0; k0 < 2048; k0 += 32) {
    __syncthreads();
#pragma unroll
    for (int c = 0; c < 2; c++) {
      int ch = wave * 2 + c;
      gload16(&A[(size_t)(m0 + ch * 16 + lrow) * 2048 + k0 + lseg], &Asl[ch * 512]);
    }
    __bf16 h[4][4];
#pragma unroll
    for (int i = 0; i < 4; i++) {
      float4 w = *(const float4*)&B[(size_t)(k0 + kg + i) * 2048 + n0 + ng];
      h[i][0] = (__bf16)w.x; h[i][1] = (__bf16)w.y;
      h[i][2] = (__bf16)w.z; h[i][3] = (__bf16)w.w;
    }
#pragma unroll
    for (int j = 0; j < 4; j++) {
      int n = ng + j;
      int pb = ((kg >> 3) + (n >> 2)) & 3;
      __bf16 o4[4] = {h[0][j], h[1][j], h[2][j], h[3][j]};
      *(uint2*)&BsT[n * 32 + pb * 8 + (kg & 7)] = *(uint2*)o4;
    }
    __syncthreads();

    bf16x8 af[4], bf[4];
#pragma unroll
    for (int i = 0; i < 4; i++)
      af[i] = *(const bf16x8*)&Asl[(wm + i * 16 + l16) * 32 + quad * 8];
#pragma unroll
    for (int i = 0; i < 4; i++) {
      int n = wn + i * 16 + l16;
      int pb = (quad + (n >> 2)) & 3;
      bf[i] = *(const bf16x8*)&BsT[n * 32 + pb * 8];
    }
#pragma unroll
    for (int mi = 0; mi < 4; mi++)
#pragma unroll
      for (int ni = 0; ni < 4; ni++)
        acc[mi][ni] = __builtin_amdgcn_mfma_f32_16x16x32_bf16(
            af[mi], bf[ni], acc[mi][ni], 0, 0, 0);
  }

#pragma unroll
  for (int mi = 0; mi < 4; mi++)
#pragma unroll
    for (int ni = 0; ni < 4; ni++)
#pragma unroll
      for (int r = 0; r < 4; r++) {
        int row = m0 + wm + mi * 16 + quad * 4 + r;
        int col = n0 + wn + ni * 16 + l16;
        Cp[(size_t)row * 2048 + col] = acc[mi][ni][r];
      }
}

// ---------------------------------------------------------------------------
// MQA causal flash attention, MFMA, fixed-base streaming softmax.
// ROUND 21 = EXACT round-9 attn (byte-identical, no setprio). Two
// consecutive container failures occurred only on the +setprio variant;
// round-9's source ran clean at 286.5 us. Locking in the verified best.
// ---------------------------------------------------------------------------
#define KS_LD 136
#define VT_LD 72
#define PR_LD 72

__global__ __launch_bounds__(256) void mqa_attn_mfma(
    const __bf16* Q, const __bf16* __restrict__ Km,
    const __bf16* __restrict__ Vm, __bf16* O)
{
  __shared__ __align__(16) __bf16 Ks[64 * KS_LD];
  __shared__ __align__(16) __bf16 VsT[128 * VT_LD];
  __shared__ __align__(16) __bf16 Pr[4][32 * PR_LD];

  const int tid = threadIdx.x, wave = tid >> 6, lane = tid & 63;
  const int quad = lane >> 4, l16 = lane & 15;
  const int t = blockIdx.x >> 1, bat = blockIdx.x & 1;
  const int hg = blockIdx.y & 3, flip = blockIdx.y >> 2;
  const int qt = flip ? (63 - t) : t;
  const int h = hg * 4 + wave;
  const int q0 = qt * 32;
  const size_t qgrow = (size_t)bat * 2048 + q0;
  const float SCL2 = 0.08838834764831845f * 1.4426950408889634f;  // scale*log2e

  // Q regs: lane holds Q[qrow=l16(+16mi)][d=ks*32+quad*8+j] — serves as the
  // B-frag of Q (B[k=d][n=qrow]) for the S^T MFMA.
  bf16x8 qf[2][4];
#pragma unroll
  for (int mi = 0; mi < 2; mi++)
#pragma unroll
    for (int ks = 0; ks < 4; ks++)
      qf[mi][ks] = *(const bf16x8*)(Q + (qgrow + mi * 16 + l16) * 2048 +
                                    h * 128 + ks * 32 + quad * 8);

  bf16x8 ones;
#pragma unroll
  for (int i = 0; i < 8; i++) ones[i] = (__bf16)1.0f;

  f32x4 oa[2][8];
#pragma unroll
  for (int mi = 0; mi < 2; mi++)
#pragma unroll
    for (int nt = 0; nt < 8; nt++) oa[mi][nt] = (f32x4){0.f, 0.f, 0.f, 0.f};
  f32x4 lacc[2];
  lacc[0] = (f32x4){0.f, 0.f, 0.f, 0.f};
  lacc[1] = (f32x4){0.f, 0.f, 0.f, 0.f};

  const __bf16* Kb = Km + (size_t)bat * 2048 * 128;
  const __bf16* Vb = Vm + (size_t)bat * 2048 * 128;
  const int qmax = q0 + 31;

  for (int sc = 0; sc <= qmax; sc += 64) {
    __syncthreads();
    // --- stage K[key][d] ---
#pragma unroll
    for (int i = 0; i < 4; i++) {
      int v = tid + i * 256;
      int row = v >> 4, dseg = (v & 15) * 8;
      int kr = sc + row; if (kr > 2047) kr = 2047;
      *(bf16x8*)&Ks[row * KS_LD + dseg] =
          *(const bf16x8*)&Kb[(size_t)kr * 128 + dseg];
    }
    // --- stage V transposed [d][key], rotated 8-key blocks ---
#pragma unroll
    for (int i = 0; i < 2; i++) {
      int g = tid + i * 256;
      int dg = (g & 31) * 4, kg2 = (g >> 5) * 4;
      union { uint2 u; unsigned short s[4]; } a[4], o;
#pragma unroll
      for (int i2 = 0; i2 < 4; i2++) {
        int kr = sc + kg2 + i2; if (kr > 2047) kr = 2047;
        a[i2].u = *(const uint2*)&Vb[(size_t)kr * 128 + dg];
      }
#pragma unroll
      for (int j = 0; j < 4; j++) {
        int d = dg + j;
        int pb = ((kg2 >> 3) + (d >> 2)) & 7;
        o.s[0] = a[0].s[j]; o.s[1] = a[1].s[j];
        o.s[2] = a[2].s[j]; o.s[3] = a[3].s[j];
        *(uint2*)&VsT[d * VT_LD + pb * 8 + (kg2 & 7)] = o.u;
      }
    }
    __syncthreads();

    // --- S^T = K @ Q^T : D reg r = S^T[key=kt*16+quad*4+r][qrow=l16(+16mi)] ---
    f32x4 sf[2][4];
#pragma unroll
    for (int mi = 0; mi < 2; mi++)
#pragma unroll
      for (int kt = 0; kt < 4; kt++) sf[mi][kt] = (f32x4){0.f, 0.f, 0.f, 0.f};
#pragma unroll
    for (int ks = 0; ks < 4; ks++)
#pragma unroll
      for (int kt = 0; kt < 4; kt++) {
        bf16x8 kf = *(const bf16x8*)&Ks[(kt * 16 + l16) * KS_LD + ks * 32 + quad * 8];
        sf[0][kt] = __builtin_amdgcn_mfma_f32_16x16x32_bf16(kf, qf[0][ks], sf[0][kt], 0, 0, 0);
        sf[1][kt] = __builtin_amdgcn_mfma_f32_16x16x32_bf16(kf, qf[1][ks], sf[1][kt], 0, 0, 0);
      }

    // --- P = exp2(S*SCL2), Pr[qrow][key] via b64 (4 contiguous keys/reg) ---
    __bf16* prw = Pr[wave];
    if (sc + 64 > q0) {  // uniform: only the diagonal chunk needs the mask
#pragma unroll
      for (int mi = 0; mi < 2; mi++) {
        int qrow = q0 + mi * 16 + l16;
#pragma unroll
        for (int kt = 0; kt < 4; kt++) {
          int kbase = sc + kt * 16 + quad * 4;
          __bf16 h4[4];
#pragma unroll
          for (int r = 0; r < 4; r++) {
            float p = (kbase + r <= qrow) ? exp2f(sf[mi][kt][r] * SCL2) : 0.f;
            h4[r] = (__bf16)p;
          }
          *(uint2*)&prw[(mi * 16 + l16) * PR_LD + kt * 16 + quad * 4] = *(uint2*)h4;
        }
      }
    } else {
#pragma unroll
      for (int mi = 0; mi < 2; mi++)
#pragma unroll
        for (int kt = 0; kt < 4; kt++) {
          __bf16 h4[4];
#pragma unroll
          for (int r = 0; r < 4; r++) h4[r] = (__bf16)exp2f(sf[mi][kt][r] * SCL2);
          *(uint2*)&prw[(mi * 16 + l16) * PR_LD + kt * 16 + quad * 4] = *(uint2*)h4;
        }
    }

    // --- O += P @ V ; l += P @ 1 (rowsum via MFMA) ---
#pragma unroll
    for (int ks2 = 0; ks2 < 2; ks2++) {
      bf16x8 pf0 = *(const bf16x8*)&prw[(l16) * PR_LD + ks2 * 32 + quad * 8];
      bf16x8 pf1 = *(const bf16x8*)&prw[(16 + l16) * PR_LD + ks2 * 32 + quad * 8];
      lacc[0] = __builtin_amdgcn_mfma_f32_16x16x32_bf16(pf0, ones, lacc[0], 0, 0, 0);
      lacc[1] = __builtin_amdgcn_mfma_f32_16x16x32_bf16(pf1, ones, lacc[1], 0, 0, 0);
#pragma unroll
      for (int nt = 0; nt < 8; nt++) {
        int d = nt * 16 + l16;
        int pb = ((ks2 * 4 + quad) + (d >> 2)) & 7;
        bf16x8 vf = *(const bf16x8*)&VsT[d * VT_LD + pb * 8];
        oa[0][nt] = __builtin_amdgcn_mfma_f32_16x16x32_bf16(pf0, vf, oa[0][nt], 0, 0, 0);
        oa[1][nt] = __builtin_amdgcn_mfma_f32_16x16x32_bf16(pf1, vf, oa[1][nt], 0, 0, 0);
      }
    }
  }

  // epilogue: O[row] = oa / l   (l > 0: diagonal key always unmasked)
#pragma unroll
  for (int mi = 0; mi < 2; mi++)
#pragma unroll
    for (int r = 0; r < 4; r++) {
      float inv = 1.f / lacc[mi][r];
      size_t row = qgrow + mi * 16 + quad * 4 + r;
#pragma unroll
      for (int nt = 0; nt < 8; nt++)
        O[row * 2048 + h * 128 + nt * 16 + l16] = (__bf16)(oa[mi][nt][r] * inv);
    }
}

// ---------------------------------------------------------------------------
// Memory plan:
//   ws   : q / at (in-place) 16.78 MB | WoT 8.39 MB (only if ws_size allows)
//   d_out: xb | WqT | WkT | WvT | k | v 28.3 MB  (dead before final GEMM)
// Dispatches: prep_all -> gemm_qkv -> mqa_attn -> gemm_out  (4 total)
// ---------------------------------------------------------------------------
extern "C" void kernel_launch(void* const* d_in, const int* in_sizes, int n_in,
                              void* d_out, int out_size, void* d_ws, size_t ws_size,
                              hipStream_t stream) {
  const float* x  = (const float*)d_in[0];
  const float* Wq = (const float*)d_in[1];
  const float* Wk = (const float*)d_in[2];
  const float* Wv = (const float*)d_in[3];
  const float* Wo = (const float*)d_in[4];
  float* out = (float*)d_out;

  __bf16* q   = (__bf16*)d_ws;
  __bf16* WoT = (__bf16*)((char*)d_ws + 16777216);
  const bool have_wot = ws_size >= (size_t)(16777216 + 8388608);

  char* ob = (char*)d_out;
  __bf16* xb  = (__bf16*)(ob);
  __bf16* WqT = (__bf16*)(ob + 16777216);
  __bf16* WkT = (__bf16*)(ob + 25165824);
  __bf16* WvT = (__bf16*)(ob + 25690112);
  __bf16* kb  = (__bf16*)(ob + 26214400);
  __bf16* vb  = (__bf16*)(ob + 27262976);

  dim3 blk(256);
  const int prep_blocks = have_wot ? 6272 : 5248;
  prep_all<<<prep_blocks, blk, 0, stream>>>(x, Wq, Wk, Wv, Wo,
                                            xb, WqT, WkT, WvT, WoT);
  gemm_qkv<<<dim3(18, 32), blk, 0, stream>>>(xb, WqT, WkT, WvT, q, kb, vb);
  mqa_attn_mfma<<<dim3(64, 8, 1), blk, 0, stream>>>(q, kb, vb, q);
  if (have_wot)
    gemm_out_bt<<<dim3(16, 32), blk, 0, stream>>>(q, WoT, out);
  else
    gemm_out_f32b<<<dim3(16, 32), blk, 0, stream>>>(q, Wo, out);
}

// Round 14
// 275.284 us; speedup vs baseline: 1.2390x; 1.0403x over previous
//
#include <hip/hip_runtime.h>

typedef __bf16 bf16x8 __attribute__((ext_vector_type(8)));
typedef float f32x4 __attribute__((ext_vector_type(4)));

// Async global->LDS, 16B per lane. LDS dest is wave-uniform base + lane*16.
__device__ inline void gload16(const __bf16* g, __bf16* l) {
  __builtin_amdgcn_global_load_lds(
      (const __attribute__((address_space(1))) unsigned int*)g,
      (__attribute__((address_space(3))) unsigned int*)l, 16, 0, 0);
}

// ---------------------------------------------------------------------------
// Fused prep — conv_bf16 + all transpose_w in ONE dispatch (round-9 win).
// ---------------------------------------------------------------------------
__device__ inline void tw_body(const float* __restrict__ W,
                               __bf16* __restrict__ WT, int Kd, int Nd,
                               int c0, int r0, int tid, __bf16* Ts)
{
#pragma unroll
  for (int i = 0; i < 4; i++) {
    int row = (tid >> 4) + i * 16, cv = (tid & 15) * 4;
    float4 w = *(const float4*)&W[(size_t)(r0 + row) * Nd + c0 + cv];
    Ts[(cv + 0) * 72 + row] = (__bf16)w.x;
    Ts[(cv + 1) * 72 + row] = (__bf16)w.y;
    Ts[(cv + 2) * 72 + row] = (__bf16)w.z;
    Ts[(cv + 3) * 72 + row] = (__bf16)w.w;
  }
  __syncthreads();
#pragma unroll
  for (int i = 0; i < 4; i++) {
    int n = (tid >> 4) + i * 16, kseg = (tid & 15) * 4;
    *(uint2*)&WT[(size_t)(c0 + n) * Kd + r0 + kseg] = *(uint2*)&Ts[n * 72 + kseg];
  }
}

__global__ __launch_bounds__(256) void prep_all(
    const float* __restrict__ x,  const float* __restrict__ Wq,
    const float* __restrict__ Wk, const float* __restrict__ Wv,
    const float* __restrict__ Wo,
    __bf16* __restrict__ xb,  __bf16* __restrict__ WqT,
    __bf16* __restrict__ WkT, __bf16* __restrict__ WvT,
    __bf16* __restrict__ WoT)
{
  __shared__ __bf16 Ts[64 * 72];
  const int b = blockIdx.x, tid = threadIdx.x;
  if (b < 4096) {
    size_t i = ((size_t)b * 256 + tid) * 8;
    float4 a = *(const float4*)&x[i];
    float4 c = *(const float4*)&x[i + 4];
    bf16x8 h;
    h[0] = (__bf16)a.x; h[1] = (__bf16)a.y; h[2] = (__bf16)a.z; h[3] = (__bf16)a.w;
    h[4] = (__bf16)c.x; h[5] = (__bf16)c.y; h[6] = (__bf16)c.z; h[7] = (__bf16)c.w;
    *(bf16x8*)&xb[i] = h;
  } else if (b < 5120) {
    int idx = b - 4096;
    tw_body(Wq, WqT, 2048, 2048, (idx & 31) * 64, (idx >> 5) * 64, tid, Ts);
  } else if (b < 5184) {
    int idx = b - 5120;
    tw_body(Wk, WkT, 2048, 128, (idx & 1) * 64, (idx >> 1) * 64, tid, Ts);
  } else if (b < 5248) {
    int idx = b - 5184;
    tw_body(Wv, WvT, 2048, 128, (idx & 1) * 64, (idx >> 1) * 64, tid, Ts);
  } else {
    int idx = b - 5248;
    tw_body(Wo, WoT, 2048, 2048, (idx & 31) * 64, (idx >> 5) * 64, tid, Ts);
  }
}

// ---------------------------------------------------------------------------
// Fused q/k/v projection GEMM. ROUND 22: BK=64 single-buffer — same 32 KB
// LDS as the dbuf BK=32 version (occupancy unchanged), same proven sync
// skeleton (barrier; stage; barrier; compute), but barrier-drain pairs
// 64 -> 32 and MFMA per drain 16 -> 32. LDS kept as TWO 32-col k-slice
// panels [2][128*32] so fragment reads keep the conflict-free 64-B row
// stride (a flat [128][64] layout would be a 16-way bank conflict).
// XCD-bijective remap retained.
// ---------------------------------------------------------------------------
__global__ __launch_bounds__(256) void gemm_qkv(
    const __bf16* __restrict__ A, const __bf16* __restrict__ WqT,
    const __bf16* __restrict__ WkT, const __bf16* __restrict__ WvT,
    __bf16* __restrict__ Cq, __bf16* __restrict__ Ck, __bf16* __restrict__ Cv)
{
  __shared__ __align__(16) __bf16 Asl[2][128 * 32];   // [k-slice panel]
  __shared__ __align__(16) __bf16 Bsl[2][128 * 32];
  const int tid = threadIdx.x, wave = tid >> 6, lane = tid & 63;
  const int quad = lane >> 4, l16 = lane & 15;
  int bid = blockIdx.x + 18 * blockIdx.y;       // linearized (x fastest)
  bid = (bid & 7) * 72 + (bid >> 3);            // XCD-contiguous remap
  const int nb = bid % 18, m0 = (bid / 18) * 128;
  const __bf16* BT; __bf16* C; int ldC, c0;
  if (nb < 16)       { BT = WqT + (size_t)nb * 128 * 2048; C = Cq; ldC = 2048; c0 = nb * 128; }
  else if (nb == 16) { BT = WkT; C = Ck; ldC = 128; c0 = 0; }
  else               { BT = WvT; C = Cv; ldC = 128; c0 = 0; }
  const int wm = (wave >> 1) * 64, wn = (wave & 1) * 64;
  const int lrow = lane >> 2, lseg = (lane & 3) * 8;

  f32x4 acc[4][4];
#pragma unroll
  for (int i = 0; i < 4; i++)
#pragma unroll
    for (int j = 0; j < 4; j++) acc[i][j] = (f32x4){0.f, 0.f, 0.f, 0.f};

  for (int k0 = 0; k0 < 2048; k0 += 64) {
    __syncthreads();   // guards panel reuse (all frags of prev iter read)
#pragma unroll
    for (int c = 0; c < 2; c++) {
      int ch = wave * 2 + c;
#pragma unroll
      for (int s = 0; s < 2; s++) {
        gload16(&A[(size_t)(m0 + ch * 16 + lrow) * 2048 + k0 + s * 32 + lseg],
                &Asl[s][ch * 512]);
        gload16(&BT[(size_t)(ch * 16 + lrow) * 2048 + k0 + s * 32 + lseg],
                &Bsl[s][ch * 512]);
      }
    }
    __syncthreads();   // drains the 8 gload_lds

#pragma unroll
    for (int s = 0; s < 2; s++) {
      bf16x8 af[4], bf[4];
#pragma unroll
      for (int i = 0; i < 4; i++)
        af[i] = *(const bf16x8*)&Asl[s][(wm + i * 16 + l16) * 32 + quad * 8];
#pragma unroll
      for (int i = 0; i < 4; i++)
        bf[i] = *(const bf16x8*)&Bsl[s][(wn + i * 16 + l16) * 32 + quad * 8];
#pragma unroll
      for (int mi = 0; mi < 4; mi++)
#pragma unroll
        for (int ni = 0; ni < 4; ni++)
          acc[mi][ni] = __builtin_amdgcn_mfma_f32_16x16x32_bf16(
              af[mi], bf[ni], acc[mi][ni], 0, 0, 0);
    }
  }

#pragma unroll
  for (int mi = 0; mi < 4; mi++)
#pragma unroll
    for (int ni = 0; ni < 4; ni++)
#pragma unroll
      for (int r = 0; r < 4; r++) {
        int row = m0 + wm + mi * 16 + quad * 4 + r;
        int col = c0 + wn + ni * 16 + l16;
        C[(size_t)row * ldC + col] = (__bf16)acc[mi][ni][r];
      }
}

// ---------------------------------------------------------------------------
// Final GEMM, pure-bf16 path. Same BK=64 single-buffer structure.
// ---------------------------------------------------------------------------
__global__ __launch_bounds__(256) void gemm_out_bt(
    const __bf16* __restrict__ A, const __bf16* __restrict__ BT,
    float* __restrict__ Cp)
{
  __shared__ __align__(16) __bf16 Asl[2][128 * 32];
  __shared__ __align__(16) __bf16 Bsl[2][128 * 32];
  const int tid = threadIdx.x, wave = tid >> 6, lane = tid & 63;
  const int quad = lane >> 4, l16 = lane & 15;
  int bid = blockIdx.x + 16 * blockIdx.y;       // linearized (x fastest)
  bid = (bid & 7) * 64 + (bid >> 3);            // XCD-contiguous remap
  const int n0 = (bid & 15) * 128, m0 = (bid >> 4) * 128;
  const int wm = (wave >> 1) * 64, wn = (wave & 1) * 64;
  const int lrow = lane >> 2, lseg = (lane & 3) * 8;

  f32x4 acc[4][4];
#pragma unroll
  for (int i = 0; i < 4; i++)
#pragma unroll
    for (int j = 0; j < 4; j++) acc[i][j] = (f32x4){0.f, 0.f, 0.f, 0.f};

  for (int k0 = 0; k0 < 2048; k0 += 64) {
    __syncthreads();
#pragma unroll
    for (int c = 0; c < 2; c++) {
      int ch = wave * 2 + c;
#pragma unroll
      for (int s = 0; s < 2; s++) {
        gload16(&A[(size_t)(m0 + ch * 16 + lrow) * 2048 + k0 + s * 32 + lseg],
                &Asl[s][ch * 512]);
        gload16(&BT[(size_t)(n0 + ch * 16 + lrow) * 2048 + k0 + s * 32 + lseg],
                &Bsl[s][ch * 512]);
      }
    }
    __syncthreads();

#pragma unroll
    for (int s = 0; s < 2; s++) {
      bf16x8 af[4], bf[4];
#pragma unroll
      for (int i = 0; i < 4; i++)
        af[i] = *(const bf16x8*)&Asl[s][(wm + i * 16 + l16) * 32 + quad * 8];
#pragma unroll
      for (int i = 0; i < 4; i++)
        bf[i] = *(const bf16x8*)&Bsl[s][(wn + i * 16 + l16) * 32 + quad * 8];
#pragma unroll
      for (int mi = 0; mi < 4; mi++)
#pragma unroll
        for (int ni = 0; ni < 4; ni++)
          acc[mi][ni] = __builtin_amdgcn_mfma_f32_16x16x32_bf16(
              af[mi], bf[ni], acc[mi][ni], 0, 0, 0);
    }
  }

#pragma unroll
  for (int mi = 0; mi < 4; mi++)
#pragma unroll
    for (int ni = 0; ni < 4; ni++)
#pragma unroll
      for (int r = 0; r < 4; r++) {
        int row = m0 + wm + mi * 16 + quad * 4 + r;
        int col = n0 + wn + ni * 16 + l16;
        Cp[(size_t)row * 2048 + col] = acc[mi][ni][r];
      }
}

// ---------------------------------------------------------------------------
// Final GEMM, fallback (ws too small for WoT). Unchanged.
// ---------------------------------------------------------------------------
__global__ __launch_bounds__(256) void gemm_out_f32b(
    const __bf16* __restrict__ A, const float* __restrict__ B,
    float* __restrict__ Cp)
{
  __shared__ __align__(16) __bf16 Asl[128 * 32];
  __shared__ __align__(16) __bf16 BsT[128 * 32];
  const int tid = threadIdx.x, wave = tid >> 6, lane = tid & 63;
  const int quad = lane >> 4, l16 = lane & 15;
  const int n0 = blockIdx.x * 128, m0 = blockIdx.y * 128;
  const int wm = (wave >> 1) * 64, wn = (wave & 1) * 64;
  const int lrow = lane >> 2, lseg = (lane & 3) * 8;
  const int kg = (tid >> 5) * 4, ng = (tid & 31) * 4;

  f32x4 acc[4][4];
#pragma unroll
  for (int i = 0; i < 4; i++)
#pragma unroll
    for (int j = 0; j < 4; j++) acc[i][j] = (f32x4){0.f, 0.f, 0.f, 0.f};

  for (int k0 = 0; k0 < 2048; k0 += 32) {
    __syncthreads();
#pragma unroll
    for (int c = 0; c < 2; c++) {
      int ch = wave * 2 + c;
      gload16(&A[(size_t)(m0 + ch * 16 + lrow) * 2048 + k0 + lseg], &Asl[ch * 512]);
    }
    __bf16 h[4][4];
#pragma unroll
    for (int i = 0; i < 4; i++) {
      float4 w = *(const float4*)&B[(size_t)(k0 + kg + i) * 2048 + n0 + ng];
      h[i][0] = (__bf16)w.x; h[i][1] = (__bf16)w.y;
      h[i][2] = (__bf16)w.z; h[i][3] = (__bf16)w.w;
    }
#pragma unroll
    for (int j = 0; j < 4; j++) {
      int n = ng + j;
      int pb = ((kg >> 3) + (n >> 2)) & 3;
      __bf16 o4[4] = {h[0][j], h[1][j], h[2][j], h[3][j]};
      *(uint2*)&BsT[n * 32 + pb * 8 + (kg & 7)] = *(uint2*)o4;
    }
    __syncthreads();

    bf16x8 af[4], bf[4];
#pragma unroll
    for (int i = 0; i < 4; i++)
      af[i] = *(const bf16x8*)&Asl[(wm + i * 16 + l16) * 32 + quad * 8];
#pragma unroll
    for (int i = 0; i < 4; i++) {
      int n = wn + i * 16 + l16;
      int pb = (quad + (n >> 2)) & 3;
      bf[i] = *(const bf16x8*)&BsT[n * 32 + pb * 8];
    }
#pragma unroll
    for (int mi = 0; mi < 4; mi++)
#pragma unroll
      for (int ni = 0; ni < 4; ni++)
        acc[mi][ni] = __builtin_amdgcn_mfma_f32_16x16x32_bf16(
            af[mi], bf[ni], acc[mi][ni], 0, 0, 0);
  }

#pragma unroll
  for (int mi = 0; mi < 4; mi++)
#pragma unroll
    for (int ni = 0; ni < 4; ni++)
#pragma unroll
      for (int r = 0; r < 4; r++) {
        int row = m0 + wm + mi * 16 + quad * 4 + r;
        int col = n0 + wn + ni * 16 + l16;
        Cp[(size_t)row * 2048 + col] = acc[mi][ni][r];
      }
}

// ---------------------------------------------------------------------------
// MQA causal flash attention, MFMA, fixed-base streaming softmax.
// Byte-identical to round-9/13 best (82 us verified twice). Noise control.
// ---------------------------------------------------------------------------
#define KS_LD 136
#define VT_LD 72
#define PR_LD 72

__global__ __launch_bounds__(256) void mqa_attn_mfma(
    const __bf16* Q, const __bf16* __restrict__ Km,
    const __bf16* __restrict__ Vm, __bf16* O)
{
  __shared__ __align__(16) __bf16 Ks[64 * KS_LD];
  __shared__ __align__(16) __bf16 VsT[128 * VT_LD];
  __shared__ __align__(16) __bf16 Pr[4][32 * PR_LD];

  const int tid = threadIdx.x, wave = tid >> 6, lane = tid & 63;
  const int quad = lane >> 4, l16 = lane & 15;
  const int t = blockIdx.x >> 1, bat = blockIdx.x & 1;
  const int hg = blockIdx.y & 3, flip = blockIdx.y >> 2;
  const int qt = flip ? (63 - t) : t;
  const int h = hg * 4 + wave;
  const int q0 = qt * 32;
  const size_t qgrow = (size_t)bat * 2048 + q0;
  const float SCL2 = 0.08838834764831845f * 1.4426950408889634f;  // scale*log2e

  // Q regs: lane holds Q[qrow=l16(+16mi)][d=ks*32+quad*8+j] — serves as the
  // B-frag of Q (B[k=d][n=qrow]) for the S^T MFMA.
  bf16x8 qf[2][4];
#pragma unroll
  for (int mi = 0; mi < 2; mi++)
#pragma unroll
    for (int ks = 0; ks < 4; ks++)
      qf[mi][ks] = *(const bf16x8*)(Q + (qgrow + mi * 16 + l16) * 2048 +
                                    h * 128 + ks * 32 + quad * 8);

  bf16x8 ones;
#pragma unroll
  for (int i = 0; i < 8; i++) ones[i] = (__bf16)1.0f;

  f32x4 oa[2][8];
#pragma unroll
  for (int mi = 0; mi < 2; mi++)
#pragma unroll
    for (int nt = 0; nt < 8; nt++) oa[mi][nt] = (f32x4){0.f, 0.f, 0.f, 0.f};
  f32x4 lacc[2];
  lacc[0] = (f32x4){0.f, 0.f, 0.f, 0.f};
  lacc[1] = (f32x4){0.f, 0.f, 0.f, 0.f};

  const __bf16* Kb = Km + (size_t)bat * 2048 * 128;
  const __bf16* Vb = Vm + (size_t)bat * 2048 * 128;
  const int qmax = q0 + 31;

  for (int sc = 0; sc <= qmax; sc += 64) {
    __syncthreads();
    // --- stage K[key][d] ---
#pragma unroll
    for (int i = 0; i < 4; i++) {
      int v = tid + i * 256;
      int row = v >> 4, dseg = (v & 15) * 8;
      int kr = sc + row; if (kr > 2047) kr = 2047;
      *(bf16x8*)&Ks[row * KS_LD + dseg] =
          *(const bf16x8*)&Kb[(size_t)kr * 128 + dseg];
    }
    // --- stage V transposed [d][key], rotated 8-key blocks ---
#pragma unroll
    for (int i = 0; i < 2; i++) {
      int g = tid + i * 256;
      int dg = (g & 31) * 4, kg2 = (g >> 5) * 4;
      union { uint2 u; unsigned short s[4]; } a[4], o;
#pragma unroll
      for (int i2 = 0; i2 < 4; i2++) {
        int kr = sc + kg2 + i2; if (kr > 2047) kr = 2047;
        a[i2].u = *(const uint2*)&Vb[(size_t)kr * 128 + dg];
      }
#pragma unroll
      for (int j = 0; j < 4; j++) {
        int d = dg + j;
        int pb = ((kg2 >> 3) + (d >> 2)) & 7;
        o.s[0] = a[0].s[j]; o.s[1] = a[1].s[j];
        o.s[2] = a[2].s[j]; o.s[3] = a[3].s[j];
        *(uint2*)&VsT[d * VT_LD + pb * 8 + (kg2 & 7)] = o.u;
      }
    }
    __syncthreads();

    // --- S^T = K @ Q^T : D reg r = S^T[key=kt*16+quad*4+r][qrow=l16(+16mi)] ---
    f32x4 sf[2][4];
#pragma unroll
    for (int mi = 0; mi < 2; mi++)
#pragma unroll
      for (int kt = 0; kt < 4; kt++) sf[mi][kt] = (f32x4){0.f, 0.f, 0.f, 0.f};
#pragma unroll
    for (int ks = 0; ks < 4; ks++)
#pragma unroll
      for (int kt = 0; kt < 4; kt++) {
        bf16x8 kf = *(const bf16x8*)&Ks[(kt * 16 + l16) * KS_LD + ks * 32 + quad * 8];
        sf[0][kt] = __builtin_amdgcn_mfma_f32_16x16x32_bf16(kf, qf[0][ks], sf[0][kt], 0, 0, 0);
        sf[1][kt] = __builtin_amdgcn_mfma_f32_16x16x32_bf16(kf, qf[1][ks], sf[1][kt], 0, 0, 0);
      }

    // --- P = exp2(S*SCL2), Pr[qrow][key] via b64 (4 contiguous keys/reg) ---
    __bf16* prw = Pr[wave];
    if (sc + 64 > q0) {  // uniform: only the diagonal chunk needs the mask
#pragma unroll
      for (int mi = 0; mi < 2; mi++) {
        int qrow = q0 + mi * 16 + l16;
#pragma unroll
        for (int kt = 0; kt < 4; kt++) {
          int kbase = sc + kt * 16 + quad * 4;
          __bf16 h4[4];
#pragma unroll
          for (int r = 0; r < 4; r++) {
            float p = (kbase + r <= qrow) ? exp2f(sf[mi][kt][r] * SCL2) : 0.f;
            h4[r] = (__bf16)p;
          }
          *(uint2*)&prw[(mi * 16 + l16) * PR_LD + kt * 16 + quad * 4] = *(uint2*)h4;
        }
      }
    } else {
#pragma unroll
      for (int mi = 0; mi < 2; mi++)
#pragma unroll
        for (int kt = 0; kt < 4; kt++) {
          __bf16 h4[4];
#pragma unroll
          for (int r = 0; r < 4; r++) h4[r] = (__bf16)exp2f(sf[mi][kt][r] * SCL2);
          *(uint2*)&prw[(mi * 16 + l16) * PR_LD + kt * 16 + quad * 4] = *(uint2*)h4;
        }
    }

    // --- O += P @ V ; l += P @ 1 (rowsum via MFMA) ---
#pragma unroll
    for (int ks2 = 0; ks2 < 2; ks2++) {
      bf16x8 pf0 = *(const bf16x8*)&prw[(l16) * PR_LD + ks2 * 32 + quad * 8];
      bf16x8 pf1 = *(const bf16x8*)&prw[(16 + l16) * PR_LD + ks2 * 32 + quad * 8];
      lacc[0] = __builtin_amdgcn_mfma_f32_16x16x32_bf16(pf0, ones, lacc[0], 0, 0, 0);
      lacc[1] = __builtin_amdgcn_mfma_f32_16x16x32_bf16(pf1, ones, lacc[1], 0, 0, 0);
#pragma unroll
      for (int nt = 0; nt < 8; nt++) {
        int d = nt * 16 + l16;
        int pb = ((ks2 * 4 + quad) + (d >> 2)) & 7;
        bf16x8 vf = *(const bf16x8*)&VsT[d * VT_LD + pb * 8];
        oa[0][nt] = __builtin_amdgcn_mfma_f32_16x16x32_bf16(pf0, vf, oa[0][nt], 0, 0, 0);
        oa[1][nt] = __builtin_amdgcn_mfma_f32_16x16x32_bf16(pf1, vf, oa[1][nt], 0, 0, 0);
      }
    }
  }

  // epilogue: O[row] = oa / l   (l > 0: diagonal key always unmasked)
#pragma unroll
  for (int mi = 0; mi < 2; mi++)
#pragma unroll
    for (int r = 0; r < 4; r++) {
      float inv = 1.f / lacc[mi][r];
      size_t row = qgrow + mi * 16 + quad * 4 + r;
#pragma unroll
      for (int nt = 0; nt < 8; nt++)
        O[row * 2048 + h * 128 + nt * 16 + l16] = (__bf16)(oa[mi][nt][r] * inv);
    }
}

// ---------------------------------------------------------------------------
// Memory plan:
//   ws   : q / at (in-place) 16.78 MB | WoT 8.39 MB (only if ws_size allows)
//   d_out: xb | WqT | WkT | WvT | k | v 28.3 MB  (dead before final GEMM)
// Dispatches: prep_all -> gemm_qkv -> mqa_attn -> gemm_out  (4 total)
// ---------------------------------------------------------------------------
extern "C" void kernel_launch(void* const* d_in, const int* in_sizes, int n_in,
                              void* d_out, int out_size, void* d_ws, size_t ws_size,
                              hipStream_t stream) {
  const float* x  = (const float*)d_in[0];
  const float* Wq = (const float*)d_in[1];
  const float* Wk = (const float*)d_in[2];
  const float* Wv = (const float*)d_in[3];
  const float* Wo = (const float*)d_in[4];
  float* out = (float*)d_out;

  __bf16* q   = (__bf16*)d_ws;
  __bf16* WoT = (__bf16*)((char*)d_ws + 16777216);
  const bool have_wot = ws_size >= (size_t)(16777216 + 8388608);

  char* ob = (char*)d_out;
  __bf16* xb  = (__bf16*)(ob);
  __bf16* WqT = (__bf16*)(ob + 16777216);
  __bf16* WkT = (__bf16*)(ob + 25165824);
  __bf16* WvT = (__bf16*)(ob + 25690112);
  __bf16* kb  = (__bf16*)(ob + 26214400);
  __bf16* vb  = (__bf16*)(ob + 27262976);

  dim3 blk(256);
  const int prep_blocks = have_wot ? 6272 : 5248;
  prep_all<<<prep_blocks, blk, 0, stream>>>(x, Wq, Wk, Wv, Wo,
                                            xb, WqT, WkT, WvT, WoT);
  gemm_qkv<<<dim3(18, 32), blk, 0, stream>>>(xb, WqT, WkT, WvT, q, kb, vb);
  mqa_attn_mfma<<<dim3(64, 8, 1), blk, 0, stream>>>(q, kb, vb, q);
  if (have_wot)
    gemm_out_bt<<<dim3(16, 32), blk, 0, stream>>>(q, WoT, out);
  else
    gemm_out_f32b<<<dim3(16, 32), blk, 0, stream>>>(q, Wo, out);
}